// Round 8
// baseline (2397.648 us; speedup 1.0000x reference)
//
#include <hip/hip_runtime.h>

typedef unsigned int uint;
typedef unsigned short ushort;
using short8 = __attribute__((ext_vector_type(8))) short;
using f32x4  = __attribute__((ext_vector_type(4))) float;
typedef _Float16 f16x2 __attribute__((ext_vector_type(2)));

#define DEVFN __device__ __forceinline__

constexpr int B_ = 32, T_ = 128, E_ = 256, H_ = 512, A_ = 256, V_ = 32000, S_ = 64;
constexpr int G3_ = 3 * H_;          // 1536
constexpr int OUTIN_ = E_ + 4 * H_;  // 2304
constexpr int M_ = B_ * T_;          // 4096 rows, convention row = t*32 + b

DEVFN ushort f2b(float f) {  // f32 -> bf16 RNE
  uint u = __float_as_uint(f);
  u += 0x7fffu + ((u >> 16) & 1u);
  return (ushort)(u >> 16);
}
DEVFN ushort f2h(float f) {  // f32 -> f16 bits
  union { _Float16 h; ushort u; } cv;
  cv.h = (_Float16)f;
  return cv.u;
}
DEVFN float sigmoid_f(float x) { return 1.f / (1.f + __expf(-x)); }
DEVFN float tanh_f(float x) { float e = __expf(2.f * x); return 1.f - 2.f / (e + 1.f); }

// ---------------- transpose + convert: in f32 (R x C) -> out bf16 (C x R) ----------------
__global__ __launch_bounds__(256) void transpose_k(const float* __restrict__ in,
                                                   ushort* __restrict__ out, int R, int C) {
  __shared__ __align__(16) ushort tile[64][65];
  int c0 = blockIdx.x * 64, r0 = blockIdx.y * 64;
  int tx = threadIdx.x & 63, ty = threadIdx.x >> 6;
#pragma unroll
  for (int k = 0; k < 16; k++) {
    int i = ty + k * 4;
    int r = r0 + i, c = c0 + tx;
    if (r < R && c < C) tile[tx][i] = f2b(in[(size_t)r * C + c]);
  }
  __syncthreads();
#pragma unroll
  for (int k = 0; k < 16; k++) {
    int j = ty + k * 4;
    int c = c0 + j, r = r0 + tx;
    if (r < R && c < C) out[(size_t)c * R + r] = tile[j][tx];
  }
}

__global__ void convert_k(const float* __restrict__ in, ushort* __restrict__ out, int n) {
  int i = blockIdx.x * 256 + threadIdx.x;
  if (i < n) out[i] = f2b(in[i]);
}

// ---------------- embedding gather -> bf16, rows r = t*32+b ----------------
__global__ __launch_bounds__(256) void gather_k(const int* __restrict__ tokens,
                                                const float* __restrict__ emb,
                                                ushort* __restrict__ xbf) {
  int r = blockIdx.x;
  int t = r >> 5, b = r & 31;
  int tok = tokens[b * T_ + t];
  xbf[(size_t)r * E_ + threadIdx.x] = f2b(emb[(size_t)tok * E_ + threadIdx.x]);
}

// ---------------- kq[b][a] = knowledge[b] @ wq[E+H: E+2H] + bq ----------------
__global__ __launch_bounds__(256) void kq_k(const float* __restrict__ knowledge,
                                            const float* __restrict__ wq,
                                            const float* __restrict__ bq,
                                            float* __restrict__ kq) {
  int b = blockIdx.x, a = threadIdx.x;
  const float* kn = knowledge + b * H_;
  float s = 0.f;
  for (int h = 0; h < H_; h++) s += kn[h] * wq[(size_t)(E_ + H_ + h) * A_ + a];
  kq[b * A_ + a] = s + bq[a];
}

// ---------------- generic bf16 MFMA GEMM: C = A (MxK) * Bt^T (Bt is N x K) + bias ----------------
template <int OUTBF, int PERM, int HASBIAS>
__global__ __launch_bounds__(256) void gemm_bt(const ushort* __restrict__ Ag,
                                               const ushort* __restrict__ Btg,
                                               const float* __restrict__ bias,
                                               void* __restrict__ Cg, int M, int N, int K) {
  __shared__ __align__(16) ushort Ash[128][40];
  __shared__ __align__(16) ushort Bsh[128][40];
  const int m0 = blockIdx.y * 128, n0 = blockIdx.x * 128;
  const int tid = threadIdx.x;
  const int wave = tid >> 6, lane = tid & 63, lr = lane & 15, lg = lane >> 4;
  const int wr = wave >> 1, wc = wave & 1;
  f32x4 acc[4][4] = {};
  for (int kk = 0; kk < K; kk += 32) {
    {
      int r = tid >> 2, q = tid & 3;
      *(short8*)&Ash[r][q * 8] = *(const short8*)&Ag[(size_t)(m0 + r) * K + kk + q * 8];
      *(short8*)&Bsh[r][q * 8] = *(const short8*)&Btg[(size_t)(n0 + r) * K + kk + q * 8];
      r += 64;
      *(short8*)&Ash[r][q * 8] = *(const short8*)&Ag[(size_t)(m0 + r) * K + kk + q * 8];
      *(short8*)&Bsh[r][q * 8] = *(const short8*)&Btg[(size_t)(n0 + r) * K + kk + q * 8];
    }
    __syncthreads();
    short8 af[4], bfr[4];
#pragma unroll
    for (int mi = 0; mi < 4; mi++) af[mi] = *(const short8*)&Ash[wr * 64 + mi * 16 + lr][lg * 8];
#pragma unroll
    for (int ni = 0; ni < 4; ni++) bfr[ni] = *(const short8*)&Bsh[wc * 64 + ni * 16 + lr][lg * 8];
#pragma unroll
    for (int mi = 0; mi < 4; mi++)
#pragma unroll
      for (int ni = 0; ni < 4; ni++)
        acc[mi][ni] = __builtin_amdgcn_mfma_f32_16x16x32_bf16(af[mi], bfr[ni], acc[mi][ni], 0, 0, 0);
    __syncthreads();
  }
#pragma unroll
  for (int mi = 0; mi < 4; mi++)
#pragma unroll
    for (int ni = 0; ni < 4; ni++) {
      int col = n0 + wc * 64 + ni * 16 + lr;
      float bv = HASBIAS ? bias[col] : 0.f;
#pragma unroll
      for (int r = 0; r < 4; r++) {
        int row = m0 + wr * 64 + mi * 16 + lg * 4 + r;
        int orow = PERM ? ((row & 31) << 7) + (row >> 5) : row;  // t*32+b -> b*128+t
        float v = acc[mi][ni][r] + bv;
        if (OUTBF) ((ushort*)Cg)[(size_t)orow * N + col] = f2b(v);
        else       ((float*)Cg)[(size_t)orow * N + col] = v;
      }
    }
}

// ---------------- repack w_hh f32 (K x 3H) -> f16 W2[kc][j][3][8] ----------------
// thread j, block kc: W2[((kc*512 + j)*3 + g)*8 + i] = f16(w_hh[kc*8+i][g*512+j])
__global__ __launch_bounds__(512) void w2prep_k(const float* __restrict__ w_hh,
                                                ushort* __restrict__ W2) {
  int kc = blockIdx.x, j = threadIdx.x;
  ushort* dst = W2 + ((size_t)kc * 512 + j) * 24;
#pragma unroll
  for (int g = 0; g < 3; g++) {
    short8 out;
#pragma unroll
    for (int i = 0; i < 8; i++)
      out[i] = (short)f2h(w_hh[(size_t)(kc * 8 + i) * G3_ + g * H_ + j]);
    *(short8*)&dst[g * 8] = out;
  }
}

// ---------------- GRU scan: one WG per batch row, fully CU-local ----------------
// h lives in LDS (f16, double-buffered); matvec via v_dot2_f32_f16 (f32 accumulate);
// one __syncthreads per step. No inter-WG communication of any kind.
__global__ __launch_bounds__(512, 1) void scan_k(
    const ushort* __restrict__ W2, const float* __restrict__ b_hh,
    const float* __restrict__ gi, const int* __restrict__ lengths,
    const float* __restrict__ h0, ushort* __restrict__ hpb,
    float* __restrict__ hidmem, float* __restrict__ hfinal) {
  __shared__ __align__(16) ushort hbuf[2][512];
  const int b = blockIdx.x;   // batch row
  const int j = threadIdx.x;  // h column
  const int len = lengths[b];
  const float bhr = b_hh[j], bhz = b_hh[H_ + j], bhn = b_hh[2 * H_ + j];

  float hp = h0[(size_t)b * H_ + j];
  hbuf[0][j] = f2h(hp);
  hpb[(size_t)b * H_ + j] = f2b(hp);  // slab 0 (t=0): row b
  __syncthreads();

  union HU { short8 s; f16x2 h[4]; };

#pragma unroll 1
  for (int t = 0; t < T_; t++) {
    const int cur = t & 1, nxt = cur ^ 1;
    const float* gir = gi + (size_t)(t * 32 + b) * G3_ + j;
    float g0v = gir[0], g1v = gir[H_], g2v = gir[2 * H_];

    float gr = 0.f, gz = 0.f, gn = 0.f;
#pragma unroll 8
    for (int kc = 0; kc < 64; kc++) {
      HU hv, w0, w1, w2;
      hv.s = *(const short8*)&hbuf[cur][kc * 8];
      const ushort* wp = W2 + ((size_t)kc * 512 + j) * 24;
      w0.s = *(const short8*)&wp[0];
      w1.s = *(const short8*)&wp[8];
      w2.s = *(const short8*)&wp[16];
#pragma unroll
      for (int p = 0; p < 4; p++) {
        gr = __builtin_amdgcn_fdot2(hv.h[p], w0.h[p], gr, false);
        gz = __builtin_amdgcn_fdot2(hv.h[p], w1.h[p], gz, false);
        gn = __builtin_amdgcn_fdot2(hv.h[p], w2.h[p], gn, false);
      }
    }

    float rr = sigmoid_f(g0v + gr + bhr);
    float zz = sigmoid_f(g1v + gz + bhz);
    float nn = tanh_f(g2v + rr * (gn + bhn));
    float hv_ = (1.f - zz) * nn + zz * hp;
    bool valid = t < len;
    float hx = valid ? hv_ : hp;
    hp = hx;
    hidmem[((size_t)b * T_ + t) * H_ + j] = valid ? hv_ : 0.f;
    hpb[((size_t)(t + 1) * 32 + b) * H_ + j] = f2b(hx);  // slab t+1
    hbuf[nxt][j] = f2h(hx);
    __syncthreads();
  }
  hfinal[(size_t)b * H_ + j] = hp;
}

// ---------------- MLP attention (scores + softmax + context), one block per (b,t) ----------------
__global__ __launch_bounds__(256) void attn_k(
    const float* __restrict__ qxk, const float* __restrict__ qh, const float* __restrict__ kq,
    const float* __restrict__ mk, const float* __restrict__ mem, const float* __restrict__ vvec,
    const int* __restrict__ slen, float* __restrict__ ctx) {
  __shared__ float qf[A_], vv[A_], sc[S_];
  int bx = blockIdx.x;  // b*T + t (b-major for mem L2 locality)
  int b = bx >> 7, t = bx & 127;
  int row = t * B_ + b;
  int tid = threadIdx.x;
  qf[tid] = qxk[(size_t)row * A_ + tid] + qh[(size_t)row * A_ + tid] + kq[b * A_ + tid];
  vv[tid] = vvec[tid];
  __syncthreads();
  int s = tid >> 2, q4 = tid & 3;
  const float* mkr = mk + ((size_t)(b * S_) + s) * A_;
  float part = 0.f;
#pragma unroll 4
  for (int i = 0; i < 64; i++) {
    int a = q4 + (i << 2);  // quad-interleaved -> coalesced 16B per quad
    part += tanh_f(qf[a] + mkr[a]) * vv[a];
  }
  part += __shfl_xor(part, 1, 64);
  part += __shfl_xor(part, 2, 64);
  if (q4 == 0) sc[s] = part;
  __syncthreads();
  if (tid < S_) {
    float v = (tid < slen[b]) ? sc[tid] : -1e9f;
    float mm = v;
    for (int off = 1; off < 64; off <<= 1) mm = fmaxf(mm, __shfl_xor(mm, off, 64));
    float e = __expf(v - mm);
    float ss = e;
    for (int off = 1; off < 64; off <<= 1) ss += __shfl_xor(ss, off, 64);
    sc[tid] = e / ss;
  }
  __syncthreads();
  float c0 = 0.f, c1 = 0.f;
  const float* mb = mem + (size_t)b * S_ * H_;
  for (int ss2 = 0; ss2 < S_; ss2++) {
    float w = sc[ss2];
    c0 += w * mb[ss2 * H_ + tid];
    c1 += w * mb[ss2 * H_ + tid + 256];
  }
  ctx[(size_t)row * H_ + tid] = c0;
  ctx[(size_t)row * H_ + tid + 256] = c1;
}

// ---------------- assemble out_in (bf16, masked); h_new taken from hidmem ----------------
__global__ __launch_bounds__(256) void assemble_k(
    const ushort* __restrict__ xbf, const float* __restrict__ hm,
    const float* __restrict__ knowledge, const float* __restrict__ ctxs,
    const float* __restrict__ ctxc, const int* __restrict__ lengths,
    ushort* __restrict__ outin) {
  int r = blockIdx.x;
  int t = r >> 5, b = r & 31;
  bool valid = t < lengths[b];
  int tid = threadIdx.x;
  ushort* dst = outin + (size_t)r * OUTIN_;
#pragma unroll
  for (int kblk = 0; kblk < 9; kblk++) {
    int i = kblk * 256 + tid;
    ushort v;
    if (i < E_)               v = xbf[(size_t)r * E_ + i];
    else if (i < E_ + H_)     v = f2b(hm[((size_t)b * T_ + t) * H_ + i - E_]);
    else if (i < E_ + 2 * H_) v = f2b(knowledge[b * H_ + i - (E_ + H_)]);
    else if (i < E_ + 3 * H_) v = f2b(ctxs[(size_t)r * H_ + i - (E_ + 2 * H_)]);
    else                      v = f2b(ctxc[(size_t)r * H_ + i - (E_ + 3 * H_)]);
    dst[i] = valid ? v : (ushort)0;
  }
}

// ---------------- in-place row log_softmax over V (online single-read LSE) ----------------
__global__ __launch_bounds__(256) void logsoftmax_k(float* __restrict__ logits) {
  __shared__ float redm[4], reds[4];
  float* row = logits + (size_t)blockIdx.x * V_;
  float4* r4 = (float4*)row;
  int tid = threadIdx.x;
  float m = -3.4e38f, s = 0.f;
  for (int i = tid; i < V_ / 4; i += 256) {
    float4 v = r4[i];
    float vm = fmaxf(fmaxf(v.x, v.y), fmaxf(v.z, v.w));
    float nm = fmaxf(m, vm);
    s = s * __expf(m - nm) + __expf(v.x - nm) + __expf(v.y - nm) +
        __expf(v.z - nm) + __expf(v.w - nm);
    m = nm;
  }
  for (int off = 1; off < 64; off <<= 1) {
    float om = __shfl_xor(m, off, 64), os = __shfl_xor(s, off, 64);
    float nm = fmaxf(m, om);
    s = s * __expf(m - nm) + os * __expf(om - nm);
    m = nm;
  }
  if ((tid & 63) == 0) { redm[tid >> 6] = m; reds[tid >> 6] = s; }
  __syncthreads();
  float M = fmaxf(fmaxf(redm[0], redm[1]), fmaxf(redm[2], redm[3]));
  float S = reds[0] * __expf(redm[0] - M) + reds[1] * __expf(redm[1] - M) +
            reds[2] * __expf(redm[2] - M) + reds[3] * __expf(redm[3] - M);
  float lse = M + __logf(S);
  for (int i = tid; i < V_ / 4; i += 256) {
    float4 v = r4[i];
    v.x -= lse; v.y -= lse; v.z -= lse; v.w -= lse;
    r4[i] = v;
  }
}

extern "C" void kernel_launch(void* const* d_in, const int* in_sizes, int n_in,
                              void* d_out, int out_size, void* d_ws, size_t ws_size,
                              hipStream_t stream) {
  const int*   tokens    = (const int*)  d_in[0];
  const int*   lengths   = (const int*)  d_in[1];
  const float* hidden0   = (const float*)d_in[2];
  const float* knowledge = (const float*)d_in[3];
  const float* src_mem   = (const float*)d_in[4];
  const int*   src_len   = (const int*)  d_in[5];
  const float* cue_mem   = (const float*)d_in[6];
  const int*   cue_len   = (const int*)  d_in[7];
  const float* emb       = (const float*)d_in[8];
  const float* w_ih      = (const float*)d_in[9];
  const float* w_hh      = (const float*)d_in[10];
  const float* b_ih      = (const float*)d_in[11];
  const float* b_hh      = (const float*)d_in[12];
  const float* src_wq    = (const float*)d_in[13];
  const float* src_bq    = (const float*)d_in[14];
  const float* src_wm    = (const float*)d_in[15];
  const float* src_v     = (const float*)d_in[16];
  const float* cue_wq    = (const float*)d_in[17];
  const float* cue_bq    = (const float*)d_in[18];
  const float* cue_wm    = (const float*)d_in[19];
  const float* cue_v     = (const float*)d_in[20];
  const float* w_out1    = (const float*)d_in[21];
  const float* b_out1    = (const float*)d_in[22];
  const float* w_out2    = (const float*)d_in[23];
  const float* b_out2    = (const float*)d_in[24];

  float* out_lp = (float*)d_out;                    // (B,T,V)
  float* out_hm = out_lp + (size_t)M_ * V_;         // (B,T,H)
  float* out_hf = out_hm + (size_t)M_ * H_;         // (B,H)

  // ---- scratch carved out of the (not-yet-written) logits region of d_out ----
  char* scb = (char*)d_out;
  size_t off = 0;
  auto alloc = [&](size_t bytes) -> void* {
    void* p = scb + off;
    off = (off + bytes + 255) & ~(size_t)255;
    return p;
  };
  float*  GI    = (float*) alloc((size_t)M_ * G3_ * 4);
  float*  QXKs  = (float*) alloc((size_t)M_ * A_ * 4);
  float*  QXKc  = (float*) alloc((size_t)M_ * A_ * 4);
  float*  QHs   = (float*) alloc((size_t)M_ * A_ * 4);
  float*  QHc   = (float*) alloc((size_t)M_ * A_ * 4);
  float*  CTXs  = (float*) alloc((size_t)M_ * H_ * 4);
  float*  CTXc  = (float*) alloc((size_t)M_ * H_ * 4);
  ushort* OUTIN = (ushort*)alloc((size_t)M_ * OUTIN_ * 2);
  ushort* XBF   = (ushort*)alloc((size_t)M_ * E_ * 2);
  ushort* WIHT  = (ushort*)alloc((size_t)G3_ * E_ * 2);
  ushort* WQXTs = (ushort*)alloc((size_t)A_ * E_ * 2);
  ushort* WQXTc = (ushort*)alloc((size_t)A_ * E_ * 2);
  ushort* WQHTs = (ushort*)alloc((size_t)A_ * H_ * 2);
  ushort* WQHTc = (ushort*)alloc((size_t)A_ * H_ * 2);
  ushort* WMTs  = (ushort*)alloc((size_t)A_ * H_ * 2);
  ushort* WMTc  = (ushort*)alloc((size_t)A_ * H_ * 2);
  ushort* WO1T  = (ushort*)alloc((size_t)H_ * OUTIN_ * 2);
  ushort* MEMBs = (ushort*)alloc((size_t)B_ * S_ * H_ * 2);
  ushort* MEMBc = (ushort*)alloc((size_t)B_ * S_ * H_ * 2);
  float*  MKs   = (float*) alloc((size_t)B_ * S_ * A_ * 4);
  float*  MKc   = (float*) alloc((size_t)B_ * S_ * A_ * 4);
  float*  KQs   = (float*) alloc((size_t)B_ * A_ * 4);
  float*  KQc   = (float*) alloc((size_t)B_ * A_ * 4);
  ushort* W2    = (ushort*)alloc((size_t)64 * 512 * 24 * 2);       // f16 repacked w_hh
  ushort* HPB   = (ushort*)alloc((size_t)(T_ + 1) * B_ * H_ * 2);  // bf16 h slabs

  // ---- d_ws: what must survive into the logits GEMM ----
  ushort* WO2T = (ushort*)d_ws;                                  // (V x H) bf16
  ushort* HID1 = (ushort*)((char*)d_ws + (size_t)V_ * H_ * 2);   // (M x H) bf16

  dim3 blk(256);

  // weight transposes (f32 KxN -> bf16 NxK)
  transpose_k<<<dim3(G3_ / 64, E_ / 64), blk, 0, stream>>>(w_ih, WIHT, E_, G3_);
  transpose_k<<<dim3(A_ / 64, E_ / 64), blk, 0, stream>>>(src_wq, WQXTs, E_, A_);
  transpose_k<<<dim3(A_ / 64, H_ / 64), blk, 0, stream>>>(src_wq + (size_t)E_ * A_, WQHTs, H_, A_);
  transpose_k<<<dim3(A_ / 64, E_ / 64), blk, 0, stream>>>(cue_wq, WQXTc, E_, A_);
  transpose_k<<<dim3(A_ / 64, H_ / 64), blk, 0, stream>>>(cue_wq + (size_t)E_ * A_, WQHTc, H_, A_);
  transpose_k<<<dim3(A_ / 64, H_ / 64), blk, 0, stream>>>(src_wm, WMTs, H_, A_);
  transpose_k<<<dim3(A_ / 64, H_ / 64), blk, 0, stream>>>(cue_wm, WMTc, H_, A_);
  transpose_k<<<dim3(H_ / 64, OUTIN_ / 64), blk, 0, stream>>>(w_out1, WO1T, OUTIN_, H_);
  transpose_k<<<dim3(V_ / 64, H_ / 64), blk, 0, stream>>>(w_out2, WO2T, H_, V_);
  convert_k<<<(B_ * S_ * H_ + 255) / 256, blk, 0, stream>>>(src_mem, MEMBs, B_ * S_ * H_);
  convert_k<<<(B_ * S_ * H_ + 255) / 256, blk, 0, stream>>>(cue_mem, MEMBc, B_ * S_ * H_);
  w2prep_k<<<64, dim3(512), 0, stream>>>(w_hh, W2);

  gather_k<<<M_, blk, 0, stream>>>(tokens, emb, XBF);
  kq_k<<<B_, blk, 0, stream>>>(knowledge, src_wq, src_bq, KQs);
  kq_k<<<B_, blk, 0, stream>>>(knowledge, cue_wq, cue_bq, KQc);

  // precompute GEMMs
  gemm_bt<0, 0, 1><<<dim3(G3_ / 128, M_ / 128), blk, 0, stream>>>(XBF, WIHT, b_ih, GI, M_, G3_, E_);
  gemm_bt<0, 0, 0><<<dim3(A_ / 128, M_ / 128), blk, 0, stream>>>(XBF, WQXTs, nullptr, QXKs, M_, A_, E_);
  gemm_bt<0, 0, 0><<<dim3(A_ / 128, M_ / 128), blk, 0, stream>>>(XBF, WQXTc, nullptr, QXKc, M_, A_, E_);
  gemm_bt<0, 0, 0><<<dim3(A_ / 128, (B_ * S_) / 128), blk, 0, stream>>>(MEMBs, WMTs, nullptr, MKs, B_ * S_, A_, H_);
  gemm_bt<0, 0, 0><<<dim3(A_ / 128, (B_ * S_) / 128), blk, 0, stream>>>(MEMBc, WMTc, nullptr, MKc, B_ * S_, A_, H_);

  // sequential GRU scan: one WG per batch row, fully CU-local (no inter-WG sync)
  scan_k<<<B_, dim3(512), 0, stream>>>(W2, b_hh, GI, lengths, hidden0, HPB, out_hm, out_hf);

  // parallel attention over all (b,t)
  gemm_bt<0, 0, 0><<<dim3(A_ / 128, M_ / 128), blk, 0, stream>>>(HPB, WQHTs, nullptr, QHs, M_, A_, H_);
  gemm_bt<0, 0, 0><<<dim3(A_ / 128, M_ / 128), blk, 0, stream>>>(HPB, WQHTc, nullptr, QHc, M_, A_, H_);
  attn_k<<<M_, blk, 0, stream>>>(QXKs, QHs, KQs, MKs, src_mem, src_v, src_len, CTXs);
  attn_k<<<M_, blk, 0, stream>>>(QXKc, QHc, KQc, MKc, cue_mem, cue_v, cue_len, CTXc);

  // output head
  assemble_k<<<M_, blk, 0, stream>>>(XBF, out_hm, knowledge, CTXs, CTXc, lengths, OUTIN);
  gemm_bt<1, 0, 1><<<dim3(H_ / 128, M_ / 128), blk, 0, stream>>>(OUTIN, WO1T, b_out1, HID1, M_, H_, OUTIN_);
  gemm_bt<0, 1, 1><<<dim3(V_ / 128, M_ / 128), blk, 0, stream>>>(HID1, WO2T, b_out2, out_lp, M_, V_, H_);
  logsoftmax_k<<<M_, blk, 0, stream>>>(out_lp);
}

// Round 9
// 1514.183 us; speedup vs baseline: 1.5835x; 1.5835x over previous
//
#include <hip/hip_runtime.h>

typedef unsigned int uint;
typedef unsigned short ushort;
using short8 = __attribute__((ext_vector_type(8))) short;
using f32x4  = __attribute__((ext_vector_type(4))) float;

#define DEVFN __device__ __forceinline__

constexpr int B_ = 32, T_ = 128, E_ = 256, H_ = 512, A_ = 256, V_ = 32000, S_ = 64;
constexpr int G3_ = 3 * H_;          // 1536
constexpr int OUTIN_ = E_ + 4 * H_;  // 2304
constexpr int M_ = B_ * T_;          // 4096 rows, convention row = t*32 + b

DEVFN ushort f2b(float f) {  // f32 -> bf16 RNE
  uint u = __float_as_uint(f);
  u += 0x7fffu + ((u >> 16) & 1u);
  return (ushort)(u >> 16);
}
DEVFN float b2f(ushort b) { return __uint_as_float(((uint)b) << 16); }
DEVFN float sigmoid_f(float x) { return 1.f / (1.f + __expf(-x)); }
DEVFN float tanh_f(float x) { float e = __expf(2.f * x); return 1.f - 2.f / (e + 1.f); }

// ---------------- transpose + convert: in f32 (R x C) -> out bf16 (C x R) ----------------
__global__ __launch_bounds__(256) void transpose_k(const float* __restrict__ in,
                                                   ushort* __restrict__ out, int R, int C) {
  __shared__ __align__(16) ushort tile[64][65];
  int c0 = blockIdx.x * 64, r0 = blockIdx.y * 64;
  int tx = threadIdx.x & 63, ty = threadIdx.x >> 6;
#pragma unroll
  for (int k = 0; k < 16; k++) {
    int i = ty + k * 4;
    int r = r0 + i, c = c0 + tx;
    if (r < R && c < C) tile[tx][i] = f2b(in[(size_t)r * C + c]);
  }
  __syncthreads();
#pragma unroll
  for (int k = 0; k < 16; k++) {
    int j = ty + k * 4;
    int c = c0 + j, r = r0 + tx;
    if (r < R && c < C) out[(size_t)c * R + r] = tile[j][tx];
  }
}

__global__ void convert_k(const float* __restrict__ in, ushort* __restrict__ out, int n) {
  int i = blockIdx.x * 256 + threadIdx.x;
  if (i < n) out[i] = f2b(in[i]);
}

// ---------------- embedding gather -> bf16, rows r = t*32+b ----------------
__global__ __launch_bounds__(256) void gather_k(const int* __restrict__ tokens,
                                                const float* __restrict__ emb,
                                                ushort* __restrict__ xbf) {
  int r = blockIdx.x;
  int t = r >> 5, b = r & 31;
  int tok = tokens[b * T_ + t];
  xbf[(size_t)r * E_ + threadIdx.x] = f2b(emb[(size_t)tok * E_ + threadIdx.x]);
}

// ---------------- kq[b][a] = knowledge[b] @ wq[E+H: E+2H] + bq ----------------
__global__ __launch_bounds__(256) void kq_k(const float* __restrict__ knowledge,
                                            const float* __restrict__ wq,
                                            const float* __restrict__ bq,
                                            float* __restrict__ kq) {
  int b = blockIdx.x, a = threadIdx.x;
  const float* kn = knowledge + b * H_;
  float s = 0.f;
  for (int h = 0; h < H_; h++) s += kn[h] * wq[(size_t)(E_ + H_ + h) * A_ + a];
  kq[b * A_ + a] = s + bq[a];
}

// ---------------- generic bf16 MFMA GEMM: C = A (MxK) * Bt^T (Bt is N x K) + bias ----------------
// OUTBF: 0 = f32 out, 1 = bf16 out (packed N stride), 2 = bf16 into f32-row slots (stride 2N)
template <int OUTBF, int PERM, int HASBIAS>
__global__ __launch_bounds__(256) void gemm_bt(const ushort* __restrict__ Ag,
                                               const ushort* __restrict__ Btg,
                                               const float* __restrict__ bias,
                                               void* __restrict__ Cg, int M, int N, int K) {
  __shared__ __align__(16) ushort Ash[128][40];
  __shared__ __align__(16) ushort Bsh[128][40];
  // XCD-aware bijective swizzle (all grids here have nwg % 8 == 0)
  const int nbx = gridDim.x;
  const int nwg = nbx * gridDim.y;
  const int lin = blockIdx.y * nbx + blockIdx.x;
  const int cpx = nwg >> 3;
  const int swz = (lin & 7) * cpx + (lin >> 3);
  const int m0 = (swz / nbx) * 128, n0 = (swz % nbx) * 128;
  const int tid = threadIdx.x;
  const int wave = tid >> 6, lane = tid & 63, lr = lane & 15, lg = lane >> 4;
  const int wr = wave >> 1, wc = wave & 1;
  f32x4 acc[4][4] = {};
  for (int kk = 0; kk < K; kk += 32) {
    {
      int r = tid >> 2, q = tid & 3;
      *(short8*)&Ash[r][q * 8] = *(const short8*)&Ag[(size_t)(m0 + r) * K + kk + q * 8];
      *(short8*)&Bsh[r][q * 8] = *(const short8*)&Btg[(size_t)(n0 + r) * K + kk + q * 8];
      r += 64;
      *(short8*)&Ash[r][q * 8] = *(const short8*)&Ag[(size_t)(m0 + r) * K + kk + q * 8];
      *(short8*)&Bsh[r][q * 8] = *(const short8*)&Btg[(size_t)(n0 + r) * K + kk + q * 8];
    }
    __syncthreads();
    short8 af[4], bfr[4];
#pragma unroll
    for (int mi = 0; mi < 4; mi++) af[mi] = *(const short8*)&Ash[wr * 64 + mi * 16 + lr][lg * 8];
#pragma unroll
    for (int ni = 0; ni < 4; ni++) bfr[ni] = *(const short8*)&Bsh[wc * 64 + ni * 16 + lr][lg * 8];
#pragma unroll
    for (int mi = 0; mi < 4; mi++)
#pragma unroll
      for (int ni = 0; ni < 4; ni++)
        acc[mi][ni] = __builtin_amdgcn_mfma_f32_16x16x32_bf16(af[mi], bfr[ni], acc[mi][ni], 0, 0, 0);
    __syncthreads();
  }
#pragma unroll
  for (int mi = 0; mi < 4; mi++)
#pragma unroll
    for (int ni = 0; ni < 4; ni++) {
      int col = n0 + wc * 64 + ni * 16 + lr;
      float bv = HASBIAS ? bias[col] : 0.f;
#pragma unroll
      for (int r = 0; r < 4; r++) {
        int row = m0 + wr * 64 + mi * 16 + lg * 4 + r;
        int orow = PERM ? ((row & 31) << 7) + (row >> 5) : row;  // t*32+b -> b*128+t
        float v = acc[mi][ni][r] + bv;
        if (OUTBF == 1)      ((ushort*)Cg)[(size_t)orow * N + col] = f2b(v);
        else if (OUTBF == 2) ((ushort*)Cg)[(size_t)orow * 2 * N + col] = f2b(v);
        else                 ((float*)Cg)[(size_t)orow * N + col] = v;
      }
    }
}

// ---------------- init bf16 h slab 0 ----------------
__global__ void inith_k(const float* __restrict__ h0, ushort* __restrict__ hpb) {
  int g = blockIdx.x * 256 + threadIdx.x;  // < B_*H_
  hpb[g] = f2b(h0[g]);
}

// ---------------- persistent GRU scan: 32 WGs x 128 threads, WG owns 16 h-cols ----------------
// Round-6 proven kernel: RELAXED agent atomics for flags (padded 128B slots), packed sc1
// publish via per-wave LDS tile, manual vmcnt drain of publish stores only.
__global__ __launch_bounds__(128, 1) void scan_k(
    const float* __restrict__ w_hh, const float* __restrict__ b_hh,
    const float* __restrict__ gi, const int* __restrict__ lengths,
    const float* __restrict__ h0, ushort* hpb,
    float* __restrict__ hidmem, float* __restrict__ hfinal, uint* flags) {
  __shared__ __align__(16) ushort pk[2][16][16];  // per-wave pack tile (intra-wave use only)
  const int wg = blockIdx.x;  // 0..31
  const int c0 = wg * 16;
  const int tid = threadIdx.x;
  const int wave = tid >> 6, lane = tid & 63, lr = lane & 15, lg = lane >> 4;
  const int c = c0 + lr;

  // preload bf16 weight fragments into registers (loop-invariant across all 128 steps)
  short8 wf0[16], wf1[16], wf2[16];
#pragma unroll
  for (int kk = 0; kk < 16; kk++) {
    short8 v0, v1, v2;
#pragma unroll
    for (int i = 0; i < 8; i++) {
      int k = kk * 32 + lg * 8 + i;
      v0[i] = (short)f2b(w_hh[(size_t)k * G3_ + 0 * H_ + c]);
      v1[i] = (short)f2b(w_hh[(size_t)k * G3_ + 1 * H_ + c]);
      v2[i] = (short)f2b(w_hh[(size_t)k * G3_ + 2 * H_ + c]);
    }
    wf0[kk] = v0; wf1[kk] = v1; wf2[kk] = v2;
  }
  const float bh0 = b_hh[c], bh1 = b_hh[H_ + c], bh2 = b_hh[2 * H_ + c];
  int len[4];
  float hp[4];
#pragma unroll
  for (int r = 0; r < 4; r++) {
    int bt = 16 * wave + lg * 4 + r;
    len[r] = lengths[bt];
    hp[r] = h0[(size_t)bt * H_ + c];
  }

#pragma unroll 1
  for (int t = 0; t < T_; t++) {
    // prefetch gi for this step (independent of the barrier) — overlaps poll latency
    float g0[4], g1[4], g2[4];
#pragma unroll
    for (int r = 0; r < 4; r++) {
      int bt = 16 * wave + lg * 4 + r;
      const float* gr = gi + (size_t)(t * 32 + bt) * G3_ + c;
      g0[r] = gr[0]; g1[r] = gr[H_]; g2[r] = gr[2 * H_];
    }
    // wait for all 64 producer waves to publish slab t (slab 0 from inith_k).
    if (t > 0) {
      while (true) {
        uint f = __hip_atomic_load(&flags[lane * 32], __ATOMIC_RELAXED, __HIP_MEMORY_SCOPE_AGENT);
        if (__all((int)(f >= (uint)t))) break;
        __builtin_amdgcn_s_sleep(1);
      }
    }
    asm volatile("" ::: "memory");

    // A-fragments from slab t: plain dwordx4 loads (proven in r4/r6)
    const ushort* Sb = hpb + (size_t)t * (B_ * H_);
    const int rowA = 16 * wave + lr;
    f32x4 a0 = {}, a1 = {}, a2 = {};
#pragma unroll
    for (int kk = 0; kk < 16; kk++) {
      short8 av = *(const short8*)(Sb + rowA * H_ + kk * 32 + lg * 8);
      a0 = __builtin_amdgcn_mfma_f32_16x16x32_bf16(av, wf0[kk], a0, 0, 0, 0);
      a1 = __builtin_amdgcn_mfma_f32_16x16x32_bf16(av, wf1[kk], a1, 0, 0, 0);
      a2 = __builtin_amdgcn_mfma_f32_16x16x32_bf16(av, wf2[kk], a2, 0, 0, 0);
    }

    // elementwise GRU update; stage bf16(hx) into the per-wave LDS pack tile
    ushort* Un16 = hpb + (size_t)(t + 1) * (B_ * H_);
    float hmv[4];
#pragma unroll
    for (int r = 0; r < 4; r++) {
      float rr = sigmoid_f(g0[r] + a0[r] + bh0);
      float zz = sigmoid_f(g1[r] + a1[r] + bh1);
      float nn = tanh_f(g2[r] + rr * (a2[r] + bh2));
      float hv = (1.f - zz) * nn + zz * hp[r];
      bool valid = t < len[r];
      float hx = valid ? hv : hp[r];
      hp[r] = hx;
      hmv[r] = valid ? hv : 0.f;
      pk[wave][lg * 4 + r][lr] = f2b(hx);
    }
    // pack: 16 rows x 32B per wave -> 32 dwordx4 sc1 stores
    if (lane < 32) {
      int row = lane >> 1, half = lane & 1;
      short8 v = *(const short8*)&pk[wave][row][half * 8];
      ushort* gp = Un16 + ((size_t)(16 * wave + row) * H_ + c0 + half * 8);
      asm volatile("global_store_dwordx4 %0, %1, off sc1" :: "v"(gp), "v"(v) : "memory");
    }
    // drain ONLY the publish stores, then relaxed per-wave flag (padded slot)
    asm volatile("s_waitcnt vmcnt(0)" ::: "memory");
    if (lane == 0)
      __hip_atomic_store(&flags[(wg * 2 + wave) * 32], (uint)(t + 1),
                         __ATOMIC_RELAXED, __HIP_MEMORY_SCOPE_AGENT);
    // hidmem stores off the critical path
#pragma unroll
    for (int r = 0; r < 4; r++) {
      int bt = 16 * wave + lg * 4 + r;
      hidmem[((size_t)bt * T_ + t) * H_ + c] = hmv[r];
    }
  }
#pragma unroll
  for (int r = 0; r < 4; r++) {
    int bt = 16 * wave + lg * 4 + r;
    hfinal[(size_t)bt * H_ + c] = hp[r];
  }
}

// ---------------- MLP attention (scores + softmax + context), one block per (b,t) ----------------
__global__ __launch_bounds__(256) void attn_k(
    const float* __restrict__ qxk, const float* __restrict__ qh, const float* __restrict__ kq,
    const float* __restrict__ mk, const float* __restrict__ mem, const float* __restrict__ vvec,
    const int* __restrict__ slen, float* __restrict__ ctx) {
  __shared__ float qf[A_], vv[A_], sc[S_];
  int bx = blockIdx.x;  // b*T + t (b-major for mem L2 locality)
  int b = bx >> 7, t = bx & 127;
  int row = t * B_ + b;
  int tid = threadIdx.x;
  qf[tid] = qxk[(size_t)row * A_ + tid] + qh[(size_t)row * A_ + tid] + kq[b * A_ + tid];
  vv[tid] = vvec[tid];
  __syncthreads();
  int s = tid >> 2, q4 = tid & 3;
  const float* mkr = mk + ((size_t)(b * S_) + s) * A_;
  float part = 0.f;
#pragma unroll 4
  for (int i = 0; i < 64; i++) {
    int a = q4 + (i << 2);  // quad-interleaved -> coalesced 16B per quad
    part += tanh_f(qf[a] + mkr[a]) * vv[a];
  }
  part += __shfl_xor(part, 1, 64);
  part += __shfl_xor(part, 2, 64);
  if (q4 == 0) sc[s] = part;
  __syncthreads();
  if (tid < S_) {
    float v = (tid < slen[b]) ? sc[tid] : -1e9f;
    float mm = v;
    for (int off = 1; off < 64; off <<= 1) mm = fmaxf(mm, __shfl_xor(mm, off, 64));
    float e = __expf(v - mm);
    float ss = e;
    for (int off = 1; off < 64; off <<= 1) ss += __shfl_xor(ss, off, 64);
    sc[tid] = e / ss;
  }
  __syncthreads();
  float c0 = 0.f, c1 = 0.f;
  const float* mb = mem + (size_t)b * S_ * H_;
  for (int ss2 = 0; ss2 < S_; ss2++) {
    float w = sc[ss2];
    c0 += w * mb[ss2 * H_ + tid];
    c1 += w * mb[ss2 * H_ + tid + 256];
  }
  ctx[(size_t)row * H_ + tid] = c0;
  ctx[(size_t)row * H_ + tid + 256] = c1;
}

// ---------------- assemble out_in (bf16, masked); h_new taken from hidmem ----------------
__global__ __launch_bounds__(256) void assemble_k(
    const ushort* __restrict__ xbf, const float* __restrict__ hm,
    const float* __restrict__ knowledge, const float* __restrict__ ctxs,
    const float* __restrict__ ctxc, const int* __restrict__ lengths,
    ushort* __restrict__ outin) {
  int r = blockIdx.x;
  int t = r >> 5, b = r & 31;
  bool valid = t < lengths[b];
  int tid = threadIdx.x;
  ushort* dst = outin + (size_t)r * OUTIN_;
#pragma unroll
  for (int kblk = 0; kblk < 9; kblk++) {
    int i = kblk * 256 + tid;
    ushort v;
    if (i < E_)               v = xbf[(size_t)r * E_ + i];
    else if (i < E_ + H_)     v = f2b(hm[((size_t)b * T_ + t) * H_ + i - E_]);
    else if (i < E_ + 2 * H_) v = f2b(knowledge[b * H_ + i - (E_ + H_)]);
    else if (i < E_ + 3 * H_) v = f2b(ctxs[(size_t)r * H_ + i - (E_ + 2 * H_)]);
    else                      v = f2b(ctxc[(size_t)r * H_ + i - (E_ + 3 * H_)]);
    dst[i] = valid ? v : (ushort)0;
  }
}

// ---------------- row log_softmax: bf16 logits (first half of f32 row slot) -> f32 out ----------------
// Chunks held in statically-indexed registers (no LDS, no global re-read).
__global__ __launch_bounds__(256) void logsoftmax_k(float* __restrict__ logits) {
  __shared__ float redm[4], reds[4];
  float* row = logits + (size_t)blockIdx.x * V_;
  const short8* rg = (const short8*)row;  // bf16 payload occupies first V_*2 bytes
  const int tid = threadIdx.x;
  short8 buf[16];
  float m = -3.4e38f, s = 0.f;
#pragma unroll
  for (int k = 0; k < 16; k++) {
    int i = tid + k * 256;
    if (i < V_ / 8) {
      short8 v = rg[i];
      buf[k] = v;
      float f0 = b2f((ushort)v[0]), f1 = b2f((ushort)v[1]);
      float f2 = b2f((ushort)v[2]), f3 = b2f((ushort)v[3]);
      float f4 = b2f((ushort)v[4]), f5 = b2f((ushort)v[5]);
      float f6 = b2f((ushort)v[6]), f7 = b2f((ushort)v[7]);
      float vm = fmaxf(fmaxf(fmaxf(f0, f1), fmaxf(f2, f3)),
                       fmaxf(fmaxf(f4, f5), fmaxf(f6, f7)));
      float nm = fmaxf(m, vm);
      s = s * __expf(m - nm) + __expf(f0 - nm) + __expf(f1 - nm) + __expf(f2 - nm) +
          __expf(f3 - nm) + __expf(f4 - nm) + __expf(f5 - nm) + __expf(f6 - nm) +
          __expf(f7 - nm);
      m = nm;
    }
  }
  for (int off = 1; off < 64; off <<= 1) {
    float om = __shfl_xor(m, off, 64), os = __shfl_xor(s, off, 64);
    float nm = fmaxf(m, om);
    s = s * __expf(m - nm) + os * __expf(om - nm);
    m = nm;
  }
  if ((tid & 63) == 0) { redm[tid >> 6] = m; reds[tid >> 6] = s; }
  __syncthreads();
  float M = fmaxf(fmaxf(redm[0], redm[1]), fmaxf(redm[2], redm[3]));
  float S = reds[0] * __expf(redm[0] - M) + reds[1] * __expf(redm[1] - M) +
            reds[2] * __expf(redm[2] - M) + reds[3] * __expf(redm[3] - M);
  float lse = M + __logf(S);
  __syncthreads();  // all reads of bf16 payload complete before f32 overwrite
#pragma unroll
  for (int k = 0; k < 16; k++) {
    int i = tid + k * 256;
    if (i < V_ / 8) {
      short8 v = buf[k];
      float4 o0, o1;
      o0.x = b2f((ushort)v[0]) - lse; o0.y = b2f((ushort)v[1]) - lse;
      o0.z = b2f((ushort)v[2]) - lse; o0.w = b2f((ushort)v[3]) - lse;
      o1.x = b2f((ushort)v[4]) - lse; o1.y = b2f((ushort)v[5]) - lse;
      o1.z = b2f((ushort)v[6]) - lse; o1.w = b2f((ushort)v[7]) - lse;
      *(float4*)&row[i * 8] = o0;
      *(float4*)&row[i * 8 + 4] = o1;
    }
  }
}

extern "C" void kernel_launch(void* const* d_in, const int* in_sizes, int n_in,
                              void* d_out, int out_size, void* d_ws, size_t ws_size,
                              hipStream_t stream) {
  const int*   tokens    = (const int*)  d_in[0];
  const int*   lengths   = (const int*)  d_in[1];
  const float* hidden0   = (const float*)d_in[2];
  const float* knowledge = (const float*)d_in[3];
  const float* src_mem   = (const float*)d_in[4];
  const int*   src_len   = (const int*)  d_in[5];
  const float* cue_mem   = (const float*)d_in[6];
  const int*   cue_len   = (const int*)  d_in[7];
  const float* emb       = (const float*)d_in[8];
  const float* w_ih      = (const float*)d_in[9];
  const float* w_hh      = (const float*)d_in[10];
  const float* b_ih      = (const float*)d_in[11];
  const float* b_hh      = (const float*)d_in[12];
  const float* src_wq    = (const float*)d_in[13];
  const float* src_bq    = (const float*)d_in[14];
  const float* src_wm    = (const float*)d_in[15];
  const float* src_v     = (const float*)d_in[16];
  const float* cue_wq    = (const float*)d_in[17];
  const float* cue_bq    = (const float*)d_in[18];
  const float* cue_wm    = (const float*)d_in[19];
  const float* cue_v     = (const float*)d_in[20];
  const float* w_out1    = (const float*)d_in[21];
  const float* b_out1    = (const float*)d_in[22];
  const float* w_out2    = (const float*)d_in[23];
  const float* b_out2    = (const float*)d_in[24];

  float* out_lp = (float*)d_out;                    // (B,T,V)
  float* out_hm = out_lp + (size_t)M_ * V_;         // (B,T,H)
  float* out_hf = out_hm + (size_t)M_ * H_;         // (B,H)

  // ---- scratch carved out of the (not-yet-written) logits region of d_out ----
  char* scb = (char*)d_out;
  size_t off = 0;
  auto alloc = [&](size_t bytes) -> void* {
    void* p = scb + off;
    off = (off + bytes + 255) & ~(size_t)255;
    return p;
  };
  float*  GI    = (float*) alloc((size_t)M_ * G3_ * 4);
  float*  QXKs  = (float*) alloc((size_t)M_ * A_ * 4);
  float*  QXKc  = (float*) alloc((size_t)M_ * A_ * 4);
  float*  QHs   = (float*) alloc((size_t)M_ * A_ * 4);
  float*  QHc   = (float*) alloc((size_t)M_ * A_ * 4);
  float*  CTXs  = (float*) alloc((size_t)M_ * H_ * 4);
  float*  CTXc  = (float*) alloc((size_t)M_ * H_ * 4);
  ushort* OUTIN = (ushort*)alloc((size_t)M_ * OUTIN_ * 2);
  ushort* XBF   = (ushort*)alloc((size_t)M_ * E_ * 2);
  ushort* WIHT  = (ushort*)alloc((size_t)G3_ * E_ * 2);
  ushort* WQXTs = (ushort*)alloc((size_t)A_ * E_ * 2);
  ushort* WQXTc = (ushort*)alloc((size_t)A_ * E_ * 2);
  ushort* WQHTs = (ushort*)alloc((size_t)A_ * H_ * 2);
  ushort* WQHTc = (ushort*)alloc((size_t)A_ * H_ * 2);
  ushort* WMTs  = (ushort*)alloc((size_t)A_ * H_ * 2);
  ushort* WMTc  = (ushort*)alloc((size_t)A_ * H_ * 2);
  ushort* WO1T  = (ushort*)alloc((size_t)H_ * OUTIN_ * 2);
  ushort* MEMBs = (ushort*)alloc((size_t)B_ * S_ * H_ * 2);
  ushort* MEMBc = (ushort*)alloc((size_t)B_ * S_ * H_ * 2);
  float*  MKs   = (float*) alloc((size_t)B_ * S_ * A_ * 4);
  float*  MKc   = (float*) alloc((size_t)B_ * S_ * A_ * 4);
  float*  KQs   = (float*) alloc((size_t)B_ * A_ * 4);
  float*  KQc   = (float*) alloc((size_t)B_ * A_ * 4);
  ushort* HPB   = (ushort*)alloc((size_t)(T_ + 1) * B_ * H_ * 2);  // bf16 h slabs

  // ---- d_ws: padded barrier flags + what must survive into the logits GEMM ----
  uint* FLAGS = (uint*)d_ws;                                          // 64 x 128B slots
  ushort* WO2T = (ushort*)((char*)d_ws + 8192);                       // (V x H) bf16
  ushort* HID1 = (ushort*)((char*)d_ws + 8192 + (size_t)V_ * H_ * 2); // (M x H) bf16

  dim3 blk(256);
  hipMemsetAsync(FLAGS, 0, 8192, stream);

  // weight transposes (f32 KxN -> bf16 NxK)
  transpose_k<<<dim3(G3_ / 64, E_ / 64), blk, 0, stream>>>(w_ih, WIHT, E_, G3_);
  transpose_k<<<dim3(A_ / 64, E_ / 64), blk, 0, stream>>>(src_wq, WQXTs, E_, A_);
  transpose_k<<<dim3(A_ / 64, H_ / 64), blk, 0, stream>>>(src_wq + (size_t)E_ * A_, WQHTs, H_, A_);
  transpose_k<<<dim3(A_ / 64, E_ / 64), blk, 0, stream>>>(cue_wq, WQXTc, E_, A_);
  transpose_k<<<dim3(A_ / 64, H_ / 64), blk, 0, stream>>>(cue_wq + (size_t)E_ * A_, WQHTc, H_, A_);
  transpose_k<<<dim3(A_ / 64, H_ / 64), blk, 0, stream>>>(src_wm, WMTs, H_, A_);
  transpose_k<<<dim3(A_ / 64, H_ / 64), blk, 0, stream>>>(cue_wm, WMTc, H_, A_);
  transpose_k<<<dim3(H_ / 64, OUTIN_ / 64), blk, 0, stream>>>(w_out1, WO1T, OUTIN_, H_);
  transpose_k<<<dim3(V_ / 64, H_ / 64), blk, 0, stream>>>(w_out2, WO2T, H_, V_);
  convert_k<<<(B_ * S_ * H_ + 255) / 256, blk, 0, stream>>>(src_mem, MEMBs, B_ * S_ * H_);
  convert_k<<<(B_ * S_ * H_ + 255) / 256, blk, 0, stream>>>(cue_mem, MEMBc, B_ * S_ * H_);

  gather_k<<<M_, blk, 0, stream>>>(tokens, emb, XBF);
  kq_k<<<B_, blk, 0, stream>>>(knowledge, src_wq, src_bq, KQs);
  kq_k<<<B_, blk, 0, stream>>>(knowledge, cue_wq, cue_bq, KQc);

  // precompute GEMMs
  gemm_bt<0, 0, 1><<<dim3(G3_ / 128, M_ / 128), blk, 0, stream>>>(XBF, WIHT, b_ih, GI, M_, G3_, E_);
  gemm_bt<0, 0, 0><<<dim3(A_ / 128, M_ / 128), blk, 0, stream>>>(XBF, WQXTs, nullptr, QXKs, M_, A_, E_);
  gemm_bt<0, 0, 0><<<dim3(A_ / 128, M_ / 128), blk, 0, stream>>>(XBF, WQXTc, nullptr, QXKc, M_, A_, E_);
  gemm_bt<0, 0, 0><<<dim3(A_ / 128, (B_ * S_) / 128), blk, 0, stream>>>(MEMBs, WMTs, nullptr, MKs, B_ * S_, A_, H_);
  gemm_bt<0, 0, 0><<<dim3(A_ / 128, (B_ * S_) / 128), blk, 0, stream>>>(MEMBc, WMTc, nullptr, MKc, B_ * S_, A_, H_);

  // sequential GRU scan (32 persistent WGs, reg-resident weights, padded flag barrier)
  inith_k<<<(B_ * H_) / 256, blk, 0, stream>>>(hidden0, HPB);
  scan_k<<<32, dim3(128), 0, stream>>>(w_hh, b_hh, GI, lengths, hidden0, HPB, out_hm, out_hf, FLAGS);

  // parallel attention over all (b,t)
  gemm_bt<0, 0, 0><<<dim3(A_ / 128, M_ / 128), blk, 0, stream>>>(HPB, WQHTs, nullptr, QHs, M_, A_, H_);
  gemm_bt<0, 0, 0><<<dim3(A_ / 128, M_ / 128), blk, 0, stream>>>(HPB, WQHTc, nullptr, QHc, M_, A_, H_);
  attn_k<<<M_, blk, 0, stream>>>(QXKs, QHs, KQs, MKs, src_mem, src_v, src_len, CTXs);
  attn_k<<<M_, blk, 0, stream>>>(QXKc, QHc, KQc, MKc, cue_mem, cue_v, cue_len, CTXc);

  // output head: logits as bf16 into the f32 row slots, then fused LSE+subtract
  assemble_k<<<M_, blk, 0, stream>>>(XBF, out_hm, knowledge, CTXs, CTXc, lengths, OUTIN);
  gemm_bt<1, 0, 1><<<dim3(H_ / 128, M_ / 128), blk, 0, stream>>>(OUTIN, WO1T, b_out1, HID1, M_, H_, OUTIN_);
  gemm_bt<2, 1, 1><<<dim3(V_ / 128, M_ / 128), blk, 0, stream>>>(HID1, WO2T, b_out2, out_lp, M_, V_, H_);
  logsoftmax_k<<<M_, blk, 0, stream>>>(out_lp);
}